// Round 13
// baseline (418.985 us; speedup 1.0000x reference)
//
#include <hip/hip_runtime.h>

typedef __bf16 bf16_t;
typedef bf16_t bf16x8 __attribute__((ext_vector_type(8)));
typedef bf16_t bf16x4 __attribute__((ext_vector_type(4)));
typedef float f32x4 __attribute__((ext_vector_type(4)));
typedef unsigned short u16;
typedef unsigned int u32;

#define E_TOT 524288
#define MT 64
#define NBLK (E_TOT / MT)   // 8192

__device__ __forceinline__ u16 f2bf(float f) {
  u32 u = __builtin_bit_cast(u32, f);
  u += 0x7FFFu + ((u >> 16) & 1u);
  return (u16)(u >> 16);
}

__device__ __forceinline__ bf16x8 pack8(f32x4 a, f32x4 b) {
  bf16x8 p;
  p[0] = (bf16_t)a[0]; p[1] = (bf16_t)a[1]; p[2] = (bf16_t)a[2]; p[3] = (bf16_t)a[3];
  p[4] = (bf16_t)b[0]; p[5] = (bf16_t)b[1]; p[6] = (bf16_t)b[2]; p[7] = (bf16_t)b[3];
  return p;
}

// W1F frag-ordered: idx = (((kb*4+wc)*4+nf)*64+l)*8+e   (kb = 32-wide k-chunk, 0..11)
//   holds W1^T[n=wc*64+nf*16+(l&15)][k=kb*32+(l>>4)*8+e] = W1[k*256+n]
__global__ void prep_w1f(const float* __restrict__ W1, u16* __restrict__ W1F) {
  int t = blockIdx.x * 256 + threadIdx.x;
  if (t < 98304) {
    int e  = t & 7;
    int l  = (t >> 3) & 63;
    int nf = (t >> 9) & 3;
    int wc = (t >> 11) & 3;
    int kb = t >> 13;
    int n = wc * 64 + nf * 16 + (l & 15);
    int k = kb * 32 + ((l >> 4) << 3) + e;
    W1F[t] = f2bf(W1[k * 256 + n]);
  }
}

// W2F frag-ordered: idx = ((ks*4+n2f)*64+l)*8+e
//   holds W2^T[n2=n2f*16+(l&15)][k=ks*32+(l>>4)*8+e] = W2[k*64+n2]
__global__ void prep_w2f(const float* __restrict__ W2, u16* __restrict__ W2F) {
  int t = blockIdx.x * 256 + threadIdx.x;
  if (t < 16384) {
    int e   = t & 7;
    int l   = (t >> 3) & 63;
    int n2f = (t >> 9) & 3;
    int ks  = t >> 11;
    int n2 = n2f * 16 + (l & 15);
    int k  = ks * 32 + ((l >> 4) << 3) + e;
    W2F[t] = f2bf(W2[k * 64 + n2]);
  }
}

// Fused: x = [src|dest|edge|u[batch]] (E x 384); h = relu(x@W1+b1); out = h@W2+b2
// Zero-barrier K-loop: x B-frags loaded DIRECTLY from global (L1-deduped across
// waves), W1 frags in registers. Waves run free; only sync is the Hs exchange.
__global__ void __launch_bounds__(256) edge_fused(
    const float* __restrict__ src, const float* __restrict__ dst,
    const float* __restrict__ ea, const float* __restrict__ u,
    const int* __restrict__ batch, const u16* __restrict__ W1F,
    const float* __restrict__ b1, const u16* __restrict__ W2F,
    const float* __restrict__ b2, float* __restrict__ out)
{
  __shared__ __align__(16) u16 Hs[16384];   // 32 KB, epilogue-only

  const int t    = threadIdx.x;
  const int wid  = t >> 6;        // == wc (64-col slice of HIDDEN)
  const int lane = t & 63;
  const int lr   = lane & 15;
  const int lg   = lane >> 4;
  const int e0   = blockIdx.x * MT;
  const int kk   = lg << 3;       // k-offset within a 32-chunk (0,8,16,24)

  // per-mf absolute row + batch index (4 rows per lane)
  int er[4], bidx[4];
  #pragma unroll
  for (int mf = 0; mf < 4; ++mf) {
    er[mf]   = e0 + mf * 16 + lr;
    bidx[mf] = batch[er[mf]];
  }

  f32x4 acc[4][4];   // [nf][mf] h^T frags
  #pragma unroll
  for (int i = 0; i < 4; ++i)
    #pragma unroll
    for (int j = 0; j < 4; ++j)
      acc[i][j] = (f32x4){0.f, 0.f, 0.f, 0.f};

  // ---- K loop: 12 chunks of 32, fully unrolled, NO barriers, NO LDS ----
  #pragma unroll
  for (int c = 0; c < 12; ++c) {
    // W1 frags for this chunk (4 x b128 from L2-hot frag-ordered pack)
    const u16* q = W1F + ((size_t)(c * 4 + wid) * 4) * 512 + lane * 8;
    bf16x8 wf0 = *(const bf16x8*)(q);
    bf16x8 wf1 = *(const bf16x8*)(q + 512);
    bf16x8 wf2 = *(const bf16x8*)(q + 1024);
    bf16x8 wf3 = *(const bf16x8*)(q + 1536);

    // x B-frags straight from global: 2 x dwordx4 per mf, L1-deduped across waves
    bf16x8 af[4];
    #pragma unroll
    for (int mf = 0; mf < 4; ++mf) {
      const float* p;
      if (c < 4)       p = src + (size_t)er[mf] * 128 + c * 32 + kk;
      else if (c < 8)  p = dst + (size_t)er[mf] * 128 + (c - 4) * 32 + kk;
      else if (c < 10) p = ea + (size_t)er[mf] * 64 + (c - 8) * 32 + kk;
      else             p = u + (size_t)bidx[mf] * 64 + (c - 10) * 32 + kk;
      af[mf] = pack8(*(const f32x4*)p, *(const f32x4*)(p + 4));
    }

    __builtin_amdgcn_s_setprio(1);
    #pragma unroll
    for (int mf = 0; mf < 4; ++mf) {
      acc[0][mf] = __builtin_amdgcn_mfma_f32_16x16x32_bf16(wf0, af[mf], acc[0][mf], 0, 0, 0);
      acc[1][mf] = __builtin_amdgcn_mfma_f32_16x16x32_bf16(wf1, af[mf], acc[1][mf], 0, 0, 0);
      acc[2][mf] = __builtin_amdgcn_mfma_f32_16x16x32_bf16(wf2, af[mf], acc[2][mf], 0, 0, 0);
      acc[3][mf] = __builtin_amdgcn_mfma_f32_16x16x32_bf16(wf3, af[mf], acc[3][mf], 0, 0, 0);
    }
    __builtin_amdgcn_s_setprio(0);
  }

  // ---- h^T -> Hs[64][256] bf16; 8B-unit swizzle up = uu ^ ((lr&3)<<2) ----
  #pragma unroll
  for (int nf = 0; nf < 4; ++nf) {
    f32x4 b1v = *(const f32x4*)(b1 + wid * 64 + nf * 16 + lg * 4);
    #pragma unroll
    for (int mf = 0; mf < 4; ++mf) {
      bf16x4 hb;
      #pragma unroll
      for (int rr = 0; rr < 4; ++rr)
        hb[rr] = (bf16_t)fmaxf(acc[nf][mf][rr] + b1v[rr], 0.f);
      int row = mf * 16 + lr;
      int uu = (wid * 4 + nf) * 4 + lg;
      int up = uu ^ ((lr & 3) << 2);
      *(bf16x4*)&Hs[row * 256 + up * 4] = hb;
    }
  }
  __syncthreads();   // the kernel's only barrier

  // ---- layer 2: out^T frags = mfma(W2_frag, h_frag); W2F from L1/L2 ----
  const int row2 = wid * 16 + lr;
  f32x4 d2[4];
  #pragma unroll
  for (int i = 0; i < 4; ++i) d2[i] = (f32x4){0.f, 0.f, 0.f, 0.f};
  #pragma unroll
  for (int ks = 0; ks < 8; ++ks) {
    int uu = ks * 8 + lg * 2;
    int up = uu ^ ((lr & 3) << 2);     // bit0 untouched -> b128 contiguous
    bf16x8 a2 = *(const bf16x8*)&Hs[row2 * 256 + up * 4];
    const u16* q = W2F + (size_t)ks * 2048 + lane * 8;
    #pragma unroll
    for (int n2f = 0; n2f < 4; ++n2f)
      d2[n2f] = __builtin_amdgcn_mfma_f32_16x16x32_bf16(
          *(const bf16x8*)(q + n2f * 512), a2, d2[n2f], 0, 0, 0);
  }

  #pragma unroll
  for (int n2f = 0; n2f < 4; ++n2f) {
    f32x4 b2v = *(const f32x4*)(b2 + n2f * 16 + lg * 4);
    f32x4 ov = d2[n2f] + b2v;
    *(f32x4*)&out[(size_t)(e0 + row2) * 64 + n2f * 16 + lg * 4] = ov;
  }
}

extern "C" void kernel_launch(void* const* d_in, const int* in_sizes, int n_in,
                              void* d_out, int out_size, void* d_ws, size_t ws_size,
                              hipStream_t stream) {
  const float* src  = (const float*)d_in[0];
  const float* dst  = (const float*)d_in[1];
  const float* ea   = (const float*)d_in[2];
  const float* u    = (const float*)d_in[3];
  const int* batch  = (const int*)d_in[4];
  const float* W1   = (const float*)d_in[5];
  const float* b1   = (const float*)d_in[6];
  const float* W2   = (const float*)d_in[7];
  const float* b2   = (const float*)d_in[8];
  float* out = (float*)d_out;

  u16* W1F = (u16*)d_ws;          // 98304 u16 frag-ordered W1^T
  u16* W2F = W1F + 98304;         // 16384 u16 frag-ordered W2^T

  prep_w1f<<<384, 256, 0, stream>>>(W1, W1F);
  prep_w2f<<<64, 256, 0, stream>>>(W2, W2F);
  edge_fused<<<NBLK, 256, 0, stream>>>(src, dst, ea, u, batch, W1F, b1, W2F, b2, out);
}

// Round 14
// 256.870 us; speedup vs baseline: 1.6311x; 1.6311x over previous
//
#include <hip/hip_runtime.h>

typedef __bf16 bf16_t;
typedef bf16_t bf16x8 __attribute__((ext_vector_type(8)));
typedef bf16_t bf16x4 __attribute__((ext_vector_type(4)));
typedef float f32x4 __attribute__((ext_vector_type(4)));
typedef unsigned short u16;
typedef unsigned int u32;

#define E_TOT 524288
#define MT 64
#define NBLK (E_TOT / MT)   // 8192

__device__ __forceinline__ u16 f2bf(float f) {
  u32 u = __builtin_bit_cast(u32, f);
  u += 0x7FFFu + ((u >> 16) & 1u);
  return (u16)(u >> 16);
}

__device__ __forceinline__ bf16x8 pack8(f32x4 a, f32x4 b) {
  bf16x8 p;
  p[0] = (bf16_t)a[0]; p[1] = (bf16_t)a[1]; p[2] = (bf16_t)a[2]; p[3] = (bf16_t)a[3];
  p[4] = (bf16_t)b[0]; p[5] = (bf16_t)b[1]; p[6] = (bf16_t)b[2]; p[7] = (bf16_t)b[3];
  return p;
}

__device__ __forceinline__ void gload_lds16(const void* g, void* l) {
  __builtin_amdgcn_global_load_lds(
      (const __attribute__((address_space(1))) u32*)g,
      (__attribute__((address_space(3))) u32*)l, 16, 0, 0);
}

// W1 [384][256] f32 -> 12 chunks (BK=32) of bank-swizzled W1^T bf16 (R7 layout).
// 16-B unit U = c*1024 + n*4 + j holds W1^T[n][c*32 + ((j^((n>>1)&3))*8) .. +8)
__global__ void prep_w1tc(const float* __restrict__ W1, u16* __restrict__ W1Tc) {
  int t = blockIdx.x * 256 + threadIdx.x;  // 0..98303
  if (t < 384 * 256) {
    int U = t >> 3, e = t & 7;
    int c = U >> 10, rem = U & 1023;
    int n = rem >> 2, j = rem & 3;
    int k = c * 32 + ((j ^ ((n >> 1) & 3)) << 3) + e;
    W1Tc[t] = f2bf(W1[k * 256 + n]);
  }
}

// W2F frag-ordered: idx = ((ks*4+n2f)*64+l)*8+e
//   holds W2^T[n2=n2f*16+(l&15)][k=ks*32+(l>>4)*8+e] = W2[k*64+n2]
__global__ void prep_w2f(const float* __restrict__ W2, u16* __restrict__ W2F) {
  int t = blockIdx.x * 256 + threadIdx.x;  // 0..16383
  if (t < 16384) {
    int e   = t & 7;
    int l   = (t >> 3) & 63;
    int n2f = (t >> 9) & 3;
    int ks  = t >> 11;
    int n2 = n2f * 16 + (l & 15);
    int k  = ks * 32 + ((l >> 4) << 3) + e;
    W2F[t] = f2bf(W2[k * 64 + n2]);
  }
}

// Fused: x = [src|dest|edge|u[batch]] (E x 384); h = relu(x@W1+b1); out = h@W2+b2
// R7 loop (W glds dbuf, counted vmcnt) + depth-3 A reg prefetch + swapped MFMA.
__global__ void __launch_bounds__(256) edge_fused(
    const float* __restrict__ src, const float* __restrict__ dst,
    const float* __restrict__ ea, const float* __restrict__ u,
    const int* __restrict__ batch, const u16* __restrict__ W1Tc,
    const float* __restrict__ b1, const u16* __restrict__ W2F,
    const float* __restrict__ b2, float* __restrict__ out)
{
  // 40960 B LDS: As 2 x 2048 u16 (8KB) + Wb 2 x 8192 u16 (32KB).
  // Epilogue: Hs[64][256] (16384 u16) overlays.
  __shared__ __align__(16) u16 smem[20480];
  u16* As = smem;
  u16* Wb = smem + 4096;
  u16* Hs = smem;

  const int t    = threadIdx.x;
  const int wid  = t >> 6;
  const int lane = t & 63;
  const int lr   = lane & 15;
  const int lg   = lane >> 4;
  const int e0   = blockIdx.x * MT;
  const int r    = t >> 2;        // A row owned by this thread (0..63)
  const int jcol = t & 3;         // 16B-unit within 32-col chunk
  const int bidx = batch[e0 + r];
  const int wunit = r * 4 + (jcol ^ ((r >> 1) & 3));   // A write unit (2-way max)

  auto loadA = [&](int c, f32x4* ra) {
    const float* p;
    if (c < 4)       p = src + (size_t)(e0 + r) * 128 + c * 32 + jcol * 8;
    else if (c < 8)  p = dst + (size_t)(e0 + r) * 128 + (c - 4) * 32 + jcol * 8;
    else if (c < 10) p = ea + (size_t)(e0 + r) * 64 + (c - 8) * 32 + jcol * 8;
    else             p = u + (size_t)bidx * 64 + (c - 10) * 32 + jcol * 8;
    ra[0] = *(const f32x4*)p;
    ra[1] = *(const f32x4*)(p + 4);
  };
  auto issueW = [&](int c, u16* Wn) {
    #pragma unroll
    for (int g = 0; g < 4; ++g) {
      int ub = wid * 256 + g * 64;   // wave-uniform 16B-unit base
      gload_lds16(W1Tc + ((size_t)c * 1024 + ub + lane) * 8, Wn + ub * 8);
    }
  };

  // prologue: A0,A1,A2 (HBM, depth-3) then W0,W1 (L2)
  f32x4 a0[2], a1[2], a2[2];
  loadA(0, a0);
  loadA(1, a1);
  loadA(2, a2);
  issueW(0, Wb);
  issueW(1, Wb + 8192);

  f32x4 acc[4][4];   // [nf][mf] h^T frags (swapped MFMA)
  #pragma unroll
  for (int i = 0; i < 4; ++i)
    #pragma unroll
    for (int j = 0; j < 4; ++j)
      acc[i][j] = (f32x4){0.f, 0.f, 0.f, 0.f};

  // ---- K loop: 12 chunks of 32 ----
  #pragma unroll
  for (int kb = 0; kb < 12; ++kb) {
    f32x4* cur = (kb % 3 == 0) ? a0 : (kb % 3 == 1) ? a1 : a2;   // static
    u16* Ab = As + (kb & 1) * 2048;
    u16* Wc = Wb + (kb & 1) * 8192;

    // pack + write A(kb) (compiler waits cur's own 2 loads only)
    *(bf16x8*)&Ab[wunit * 8] = pack8(cur[0], cur[1]);
    // refill this register set with A(kb+3)
    if (kb <= 8) loadA(kb + 3, cur);

    // gate: W(kb) + As writes published; newer prefetches stay in flight
    if (kb == 0)       asm volatile("s_waitcnt vmcnt(6) lgkmcnt(0)" ::: "memory");
    else if (kb <= 8)  asm volatile("s_waitcnt vmcnt(8) lgkmcnt(0)" ::: "memory");
    else if (kb == 9)  asm volatile("s_waitcnt vmcnt(6) lgkmcnt(0)" ::: "memory");
    else if (kb == 10) asm volatile("s_waitcnt vmcnt(4) lgkmcnt(0)" ::: "memory");
    else               asm volatile("s_waitcnt vmcnt(0) lgkmcnt(0)" ::: "memory");
    __builtin_amdgcn_sched_barrier(0);
    __builtin_amdgcn_s_barrier();

    __builtin_amdgcn_s_setprio(1);
    bf16x8 af[4];
    #pragma unroll
    for (int mf = 0; mf < 4; ++mf) {
      int row = mf * 16 + lr;
      af[mf] = *(const bf16x8*)&Ab[(row * 4 + (lg ^ ((row >> 1) & 3))) * 8];
    }
    #pragma unroll
    for (int nf = 0; nf < 4; ++nf) {
      int n = wid * 64 + nf * 16 + lr;
      bf16x8 wfr = *(const bf16x8*)&Wc[(n * 4 + (lg ^ ((n >> 1) & 3))) * 8];
      #pragma unroll
      for (int mf = 0; mf < 4; ++mf)
        acc[nf][mf] = __builtin_amdgcn_mfma_f32_16x16x32_bf16(wfr, af[mf], acc[nf][mf], 0, 0, 0);
    }
    __builtin_amdgcn_s_setprio(0);
    __builtin_amdgcn_s_barrier();   // all waves done reading Ab/Wc

    // stage W(kb+2) into the just-freed Wc
    if (kb <= 9) issueW(kb + 2, Wc);
  }

  // ---- h^T -> Hs[64][256] bf16 (overlays); b64 writes, up = uu ^ ((lr&3)<<2) ----
  #pragma unroll
  for (int nf = 0; nf < 4; ++nf) {
    f32x4 b1v = *(const f32x4*)(b1 + wid * 64 + nf * 16 + lg * 4);
    #pragma unroll
    for (int mf = 0; mf < 4; ++mf) {
      int row = mf * 16 + lr;
      bf16x4 hb;
      #pragma unroll
      for (int rr = 0; rr < 4; ++rr)
        hb[rr] = (bf16_t)fmaxf(acc[nf][mf][rr] + b1v[rr], 0.f);
      int uu = (wid * 4 + nf) * 4 + lg;
      int up = uu ^ ((lr & 3) << 2);
      *(bf16x4*)&Hs[row * 256 + up * 4] = hb;
    }
  }
  __syncthreads();

  // ---- layer 2: out^T frags = mfma(W2_frag, h_frag); W2F from L1/L2 ----
  const int row2 = wid * 16 + lr;
  f32x4 d2[4];
  #pragma unroll
  for (int i = 0; i < 4; ++i) d2[i] = (f32x4){0.f, 0.f, 0.f, 0.f};
  #pragma unroll
  for (int ks = 0; ks < 8; ++ks) {
    int uu = ks * 8 + lg * 2;
    int up = uu ^ ((lr & 3) << 2);     // bit0 untouched -> b128 contiguous
    bf16x8 a2 = *(const bf16x8*)&Hs[row2 * 256 + up * 4];
    const u16* q = W2F + (size_t)ks * 2048 + lane * 8;
    #pragma unroll
    for (int n2f = 0; n2f < 4; ++n2f)
      d2[n2f] = __builtin_amdgcn_mfma_f32_16x16x32_bf16(
          *(const bf16x8*)(q + n2f * 512), a2, d2[n2f], 0, 0, 0);
  }

  // ---- epilogue store: f32x4, line-complete coalescing ----
  #pragma unroll
  for (int n2f = 0; n2f < 4; ++n2f) {
    f32x4 b2v = *(const f32x4*)(b2 + n2f * 16 + lg * 4);
    f32x4 ov = d2[n2f] + b2v;
    *(f32x4*)&out[(size_t)(e0 + row2) * 64 + n2f * 16 + lg * 4] = ov;
  }
}

extern "C" void kernel_launch(void* const* d_in, const int* in_sizes, int n_in,
                              void* d_out, int out_size, void* d_ws, size_t ws_size,
                              hipStream_t stream) {
  const float* src  = (const float*)d_in[0];
  const float* dst  = (const float*)d_in[1];
  const float* ea   = (const float*)d_in[2];
  const float* u    = (const float*)d_in[3];
  const int* batch  = (const int*)d_in[4];
  const float* W1   = (const float*)d_in[5];
  const float* b1   = (const float*)d_in[6];
  const float* W2   = (const float*)d_in[7];
  const float* b2   = (const float*)d_in[8];
  float* out = (float*)d_out;

  u16* W1Tc = (u16*)d_ws;            // 12 chunks x 1024 16B-units (swizzled W1^T)
  u16* W2F  = W1Tc + 384 * 256;      // 16384 u16 frag-ordered W2^T

  prep_w1tc<<<(384 * 256 + 255) / 256, 256, 0, stream>>>(W1, W1Tc);
  prep_w2f<<<64, 256, 0, stream>>>(W2, W2F);
  edge_fused<<<NBLK, 256, 0, stream>>>(src, dst, ea, u, batch, W1Tc, b1, W2F, b2, out);
}

// Round 15
// 235.097 us; speedup vs baseline: 1.7822x; 1.0926x over previous
//
#include <hip/hip_runtime.h>

typedef __bf16 bf16_t;
typedef bf16_t bf16x8 __attribute__((ext_vector_type(8)));
typedef bf16_t bf16x4 __attribute__((ext_vector_type(4)));
typedef float f32x4 __attribute__((ext_vector_type(4)));
typedef unsigned short u16;
typedef unsigned int u32;

#define E_TOT 524288
#define MT 64
#define NBLK (E_TOT / MT)   // 8192

__device__ __forceinline__ u16 f2bf(float f) {
  u32 u = __builtin_bit_cast(u32, f);
  u += 0x7FFFu + ((u >> 16) & 1u);
  return (u16)(u >> 16);
}

__device__ __forceinline__ bf16x8 pack8(f32x4 a, f32x4 b) {
  bf16x8 p;
  p[0] = (bf16_t)a[0]; p[1] = (bf16_t)a[1]; p[2] = (bf16_t)a[2]; p[3] = (bf16_t)a[3];
  p[4] = (bf16_t)b[0]; p[5] = (bf16_t)b[1]; p[6] = (bf16_t)b[2]; p[7] = (bf16_t)b[3];
  return p;
}

// W1F frag-ordered: idx = (((kb*4+wc)*4+nf)*64+l)*8+e   (kb = 32-wide k-chunk, 0..11)
//   holds W1^T[n=wc*64+nf*16+(l&15)][k=kb*32+(l>>4)*8+e] = W1[k*256+n]
__global__ void prep_w1f(const float* __restrict__ W1, u16* __restrict__ W1F) {
  int t = blockIdx.x * 256 + threadIdx.x;
  if (t < 98304) {
    int e  = t & 7;
    int l  = (t >> 3) & 63;
    int nf = (t >> 9) & 3;
    int wc = (t >> 11) & 3;
    int kb = t >> 13;
    int n = wc * 64 + nf * 16 + (l & 15);
    int k = kb * 32 + ((l >> 4) << 3) + e;
    W1F[t] = f2bf(W1[k * 256 + n]);
  }
}

// W2F frag-ordered: idx = ((ks*4+n2f)*64+l)*8+e
//   holds W2^T[n2=n2f*16+(l&15)][k=ks*32+(l>>4)*8+e] = W2[k*64+n2]
__global__ void prep_w2f(const float* __restrict__ W2, u16* __restrict__ W2F) {
  int t = blockIdx.x * 256 + threadIdx.x;
  if (t < 16384) {
    int e   = t & 7;
    int l   = (t >> 3) & 63;
    int n2f = (t >> 9) & 3;
    int ks  = t >> 11;
    int n2 = n2f * 16 + (l & 15);
    int k  = ks * 32 + ((l >> 4) << 3) + e;
    W2F[t] = f2bf(W2[k * 64 + n2]);
  }
}

// Fused: x = [src|dest|edge|u[batch]] (E x 384); h = relu(x@W1+b1); out = h@W2+b2
// R8 structure (W1 frags in registers, swapped MFMA, A LDS dbuf) with
// counted-wait barriers (prefetches stay in flight) + fixed Hs swizzle.
__global__ void __launch_bounds__(256) edge_fused(
    const float* __restrict__ src, const float* __restrict__ dst,
    const float* __restrict__ ea, const float* __restrict__ u,
    const int* __restrict__ batch, const u16* __restrict__ W1F,
    const float* __restrict__ b1, const u16* __restrict__ W2F,
    const float* __restrict__ b2, float* __restrict__ out)
{
  // 32 KB LDS: As dbuf 2x2048 u16 (8 KB) during K-loop; Hs[64][256] bf16 overlays.
  __shared__ __align__(16) u16 smem[16384];
  u16* As = smem;
  u16* Hs = smem;

  const int t    = threadIdx.x;
  const int wid  = t >> 6;
  const int lane = t & 63;
  const int lr   = lane & 15;
  const int lg   = lane >> 4;
  const int e0   = blockIdx.x * MT;
  const int r    = t >> 2;        // A row owned by this thread
  const int jcol = t & 3;         // 16B-unit within 32-col chunk
  const int bidx = batch[e0 + r];
  const int wunit = r * 4 + (jcol ^ ((r >> 1) & 3));   // A write unit (2-way max)

  auto loadA = [&](int c, f32x4* ra) {
    const float* p;
    if (c < 4)       p = src + (size_t)(e0 + r) * 128 + c * 32 + jcol * 8;
    else if (c < 8)  p = dst + (size_t)(e0 + r) * 128 + (c - 4) * 32 + jcol * 8;
    else if (c < 10) p = ea + (size_t)(e0 + r) * 64 + (c - 8) * 32 + jcol * 8;
    else             p = u + (size_t)bidx * 64 + (c - 10) * 32 + jcol * 8;
    ra[0] = *(const f32x4*)p;
    ra[1] = *(const f32x4*)(p + 4);
  };
  auto loadW1 = [&](int c, bf16x8* wf) {
    const u16* p = W1F + ((size_t)(c * 4 + wid) * 4) * 512 + lane * 8;
    wf[0] = *(const bf16x8*)(p);
    wf[1] = *(const bf16x8*)(p + 512);
    wf[2] = *(const bf16x8*)(p + 1024);
    wf[3] = *(const bf16x8*)(p + 1536);
  };

  // prologue: A chunks 0,1 + W chunks 0,1 in flight
  f32x4 ra[2], rb[2];
  bf16x8 wA[4], wB[4];
  loadA(0, ra);
  loadW1(0, wA);
  loadA(1, rb);
  loadW1(1, wB);

  f32x4 acc[4][4];   // [nf][mf] : h^T frags (swapped MFMA)
  #pragma unroll
  for (int i = 0; i < 4; ++i)
    #pragma unroll
    for (int j = 0; j < 4; ++j)
      acc[i][j] = (f32x4){0.f, 0.f, 0.f, 0.f};

  // ---- K loop: 12 chunks of 32; counted-wait barrier (NO vmcnt drain) ----
  #pragma unroll
  for (int kb = 0; kb < 12; ++kb) {
    f32x4*  rc  = (kb & 1) ? rb : ra;
    bf16x8* wc_ = (kb & 1) ? wB : wA;
    u16* Ab = As + (kb & 1) * 2048;

    // publish A(kb) (compiler waits only rc's 2 loads), refill with A(kb+2)
    *(bf16x8*)&Ab[wunit * 8] = pack8(rc[0], rc[1]);
    if (kb <= 9) loadA(kb + 2, rc);

    // LDS-write publish only; A/W global prefetches stay in flight across barrier
    asm volatile("s_waitcnt lgkmcnt(0)" ::: "memory");
    __builtin_amdgcn_s_barrier();
    __builtin_amdgcn_sched_barrier(0);

    __builtin_amdgcn_s_setprio(1);
    bf16x8 af[4];
    #pragma unroll
    for (int mf = 0; mf < 4; ++mf) {
      int row = mf * 16 + lr;
      af[mf] = *(const bf16x8*)&Ab[(row * 4 + (lg ^ ((row >> 1) & 3))) * 8];
    }
    #pragma unroll
    for (int nf = 0; nf < 4; ++nf)
      #pragma unroll
      for (int mf = 0; mf < 4; ++mf)
        acc[nf][mf] = __builtin_amdgcn_mfma_f32_16x16x32_bf16(wc_[nf], af[mf], acc[nf][mf], 0, 0, 0);
    __builtin_amdgcn_s_setprio(0);

    // refill W regs with chunk kb+2 (register dep orders after last use)
    if (kb <= 9) loadW1(kb + 2, wc_);
  }
  __syncthreads();  // last As reads done before Hs overlay

  // ---- h^T -> Hs[64][256] bf16; FIXED swizzle up = uu ^ ((lr&3)<<2) ----
  #pragma unroll
  for (int nf = 0; nf < 4; ++nf) {
    f32x4 b1v = *(const f32x4*)(b1 + wid * 64 + nf * 16 + lg * 4);
    #pragma unroll
    for (int mf = 0; mf < 4; ++mf) {
      int row = mf * 16 + lr;
      bf16x4 hb;
      #pragma unroll
      for (int rr = 0; rr < 4; ++rr)
        hb[rr] = (bf16_t)fmaxf(acc[nf][mf][rr] + b1v[rr], 0.f);
      int uu = (wid * 4 + nf) * 4 + lg;
      int up = uu ^ ((lr & 3) << 2);
      *(bf16x4*)&Hs[row * 256 + up * 4] = hb;
    }
  }
  __syncthreads();

  // ---- layer 2: out^T frags = mfma(W2_frag, h_frag); W2F from L1/L2 ----
  const int row2 = wid * 16 + lr;
  f32x4 d2[4];
  #pragma unroll
  for (int i = 0; i < 4; ++i) d2[i] = (f32x4){0.f, 0.f, 0.f, 0.f};
  #pragma unroll
  for (int ks = 0; ks < 8; ++ks) {
    int uu = ks * 8 + lg * 2;
    int up = uu ^ ((lr & 3) << 2);     // bit0 untouched -> b128 contiguous
    bf16x8 a2 = *(const bf16x8*)&Hs[row2 * 256 + up * 4];
    const u16* q = W2F + (size_t)ks * 2048 + lane * 8;
    #pragma unroll
    for (int n2f = 0; n2f < 4; ++n2f)
      d2[n2f] = __builtin_amdgcn_mfma_f32_16x16x32_bf16(
          *(const bf16x8*)(q + n2f * 512), a2, d2[n2f], 0, 0, 0);
  }

  // ---- epilogue store: f32x4 coalesced ----
  #pragma unroll
  for (int n2f = 0; n2f < 4; ++n2f) {
    f32x4 b2v = *(const f32x4*)(b2 + n2f * 16 + lg * 4);
    f32x4 ov = d2[n2f] + b2v;
    *(f32x4*)&out[(size_t)(e0 + row2) * 64 + n2f * 16 + lg * 4] = ov;
  }
}

extern "C" void kernel_launch(void* const* d_in, const int* in_sizes, int n_in,
                              void* d_out, int out_size, void* d_ws, size_t ws_size,
                              hipStream_t stream) {
  const float* src  = (const float*)d_in[0];
  const float* dst  = (const float*)d_in[1];
  const float* ea   = (const float*)d_in[2];
  const float* u    = (const float*)d_in[3];
  const int* batch  = (const int*)d_in[4];
  const float* W1   = (const float*)d_in[5];
  const float* b1   = (const float*)d_in[6];
  const float* W2   = (const float*)d_in[7];
  const float* b2   = (const float*)d_in[8];
  float* out = (float*)d_out;

  u16* W1F = (u16*)d_ws;          // 98304 u16 frag-ordered W1^T
  u16* W2F = W1F + 98304;         // 16384 u16 frag-ordered W2^T

  prep_w1f<<<384, 256, 0, stream>>>(W1, W1F);
  prep_w2f<<<64, 256, 0, stream>>>(W2, W2F);
  edge_fused<<<NBLK, 256, 0, stream>>>(src, dst, ea, u, batch, W1F, b1, W2F, b2, out);
}